// Round 2
// baseline (1891.188 us; speedup 1.0000x reference)
//
#include <hip/hip_runtime.h>
#include <hip/hip_cooperative_groups.h>
#include <hip/hip_bf16.h>
#include <float.h>

namespace cg = cooperative_groups;

#define NS 32768
#define KER 256
#define TOUT 32513
#define NATOM 256
#define NSTEP 16
#define BATCH 8
#define NBLK 255
#define SW4(i) ((i) + (((i) >> 5) << 2))

__device__ __forceinline__ void cmax(float& ba, float& bs, float& bi,
                                     float oa, float os, float oi) {
    if (oa > ba || (oa == ba && oi < bi)) { ba = oa; bs = os; bi = oi; }
}

__device__ __forceinline__ void fma16(float acc[16], float4 dA, float4 dB,
                                      float4 q0, float4 q1, float4 q2,
                                      float4 q3, float4 q4, float4 q5) {
    float w[24] = {q0.x,q0.y,q0.z,q0.w, q1.x,q1.y,q1.z,q1.w,
                   q2.x,q2.y,q2.z,q2.w, q3.x,q3.y,q3.z,q3.w,
                   q4.x,q4.y,q4.z,q4.w, q5.x,q5.y,q5.z,q5.w};
    float dv[8] = {dA.x,dA.y,dA.z,dA.w, dB.x,dB.y,dB.z,dB.w};
#pragma unroll
    for (int i = 0; i < 8; ++i)
#pragma unroll
        for (int j = 0; j < 16; ++j)
            acc[j] = fmaf(dv[i], w[i + j], acc[j]);
}

__device__ __forceinline__ void fma8(float acc[8], float4 dA, float4 dB,
                                     float4 w0, float4 w1, float4 w2, float4 w3) {
    float w[16] = {w0.x,w0.y,w0.z,w0.w, w1.x,w1.y,w1.z,w1.w,
                   w2.x,w2.y,w2.z,w2.w, w3.x,w3.y,w3.z,w3.w};
    float dv[8] = {dA.x,dA.y,dA.z,dA.w, dB.x,dB.y,dB.z,dB.w};
#pragma unroll
    for (int i = 0; i < 8; ++i)
#pragma unroll
        for (int j = 0; j < 8; ++j)
            acc[j] = fmaf(dv[i], w[i + j], acc[j]);
}

// Full correlation of x with all 256 atoms + per-128-block abs-argmax.
// grid: (8 t-chunks of 4096, 16 atom-groups of 16, 8 batch), block 256
__global__ __launch_bounds__(256) void k_init(const float* __restrict__ x,
                                              const float* __restrict__ d,
                                              float4* __restrict__ bm) {
    const int c = blockIdx.x, og = blockIdx.y, b = blockIdx.z;
    const int tid = threadIdx.x;
    __shared__ float rs[4896];   // SW4-swizzled, covers idx 0..4351
    __shared__ float dt[4096];   // 16 atoms x 256
    const int base = c * 4096;
    const float* xp = x + (size_t)b * NS;
    for (int i4 = tid; i4 < 1088; i4 += 256) {
        const int i = i4 << 2, g = base + i;
        float4 v;
        if (g + 3 < NS) v = *(const float4*)(xp + g);
        else {
            v.x = (g     < NS) ? xp[g]     : 0.f;
            v.y = (g + 1 < NS) ? xp[g + 1] : 0.f;
            v.z = (g + 2 < NS) ? xp[g + 2] : 0.f;
            v.w = (g + 3 < NS) ? xp[g + 3] : 0.f;
        }
        *(float4*)(rs + SW4(i)) = v;
    }
    {
        const float4* ds4 = (const float4*)(d + og * 4096);
        float4* dd4 = (float4*)dt;
        for (int i = tid; i < 1024; i += 256) dd4[i] = ds4[i];
    }
    __syncthreads();
    const int t0 = tid << 4;
    for (int o = 0; o < 16; ++o) {
        const float* dr = dt + (o << 8);
        float acc[16];
#pragma unroll
        for (int j = 0; j < 16; ++j) acc[j] = 0.f;
        float4 Q0 = *(const float4*)(rs + SW4(t0));
        float4 Q1 = *(const float4*)(rs + SW4(t0 + 4));
        float4 Q2 = *(const float4*)(rs + SW4(t0 + 8));
        float4 Q3 = *(const float4*)(rs + SW4(t0 + 12));
#pragma unroll
        for (int kk = 0; kk < 256; kk += 16) {
            float4 Q4 = *(const float4*)(rs + SW4(t0 + kk + 16));
            float4 Q5 = *(const float4*)(rs + SW4(t0 + kk + 20));
            float4 d0 = *(const float4*)(dr + kk);
            float4 d1 = *(const float4*)(dr + kk + 4);
            fma16(acc, d0, d1, Q0, Q1, Q2, Q3, Q4, Q5);
            float4 P0 = *(const float4*)(rs + SW4(t0 + kk + 24));
            float4 P1 = *(const float4*)(rs + SW4(t0 + kk + 28));
            float4 d2 = *(const float4*)(dr + kk + 8);
            float4 d3 = *(const float4*)(dr + kk + 12);
            fma16(acc, d2, d3, Q2, Q3, Q4, Q5, P0, P1);
            Q0 = Q4; Q1 = Q5; Q2 = P0; Q3 = P1;
        }
        const int oglob = (og << 4) + o;
        float ba = -1.f, bsg = 0.f, bi = 3.0e7f;
#pragma unroll
        for (int j = 0; j < 16; ++j) {
            const int t = base + t0 + j;
            const float av = fabsf(acc[j]);
            if (t < TOUT && av > ba) { ba = av; bsg = acc[j]; bi = (float)(oglob * TOUT + t); }
        }
        // one 128-t block = 8 consecutive lanes
#pragma unroll
        for (int m = 4; m >= 1; m >>= 1) {
            float oa = __shfl_xor(ba, m, 8);
            float os = __shfl_xor(bsg, m, 8);
            float oi = __shfl_xor(bi, m, 8);
            cmax(ba, bsg, bi, oa, os, oi);
        }
        if ((tid & 7) == 0) {
            const int blk = (c << 5) + (tid >> 3);
            if (blk < NBLK)
                bm[(size_t)(b * NATOM + oglob) * NBLK + blk] = make_float4(ba, bsg, bi, 0.f);
        }
    }
}

// Persistent cooperative kernel: all 16 MP steps.
// grid (32 atom-groups of 8, 8 batch), block 512. One grid.sync per step.
__global__ __launch_bounds__(512) void k_iter(const float* __restrict__ x,
                                              const float* __restrict__ d,
                                              const float4* __restrict__ bm,
                                              float4* __restrict__ l2,
                                              int* __restrict__ pos_a,
                                              int* __restrict__ atom_a,
                                              float* __restrict__ amp_a) {
    cg::grid_group grid = cg::this_grid();
    const int og = blockIdx.x, b = blockIdx.y;
    const int tid = threadIdx.x;
    const int wave = tid >> 6, lane = tid & 63;
    __shared__ float dt[2048];                       // own 8 atoms
    __shared__ float sabs[2048], ssig[2048], sidx[2048];  // private bm copy
    __shared__ float rsu[1072];                      // SW4 window
    __shared__ float4 sred[8];
    __shared__ int s_pos[NSTEP], s_atom[NSTEP];
    __shared__ float s_amp[NSTEP];

    {
        const float4* ds4 = (const float4*)(d + og * 2048);
        float4* dd4 = (float4*)dt;
        if (tid < 512) dd4[tid] = ds4[tid];
    }
    for (int ii = tid; ii < 2048; ii += 512) {
        const int a = ii >> 8, i = ii & 255;
        if (i < NBLK) {
            float4 e = bm[(size_t)(b * NATOM + (og << 3) + a) * NBLK + i];
            sabs[ii] = e.x; ssig[ii] = e.y; sidx[ii] = e.z;
        } else { sabs[ii] = -1.f; ssig[ii] = 0.f; sidx[ii] = 3.0e7f; }
    }
    __syncthreads();
    // level-2 init: wave w -> atom w
    {
        float ba = -1.f, bsg = 0.f, bi = 3.0e7f;
        for (int i = lane; i < 256; i += 64)
            cmax(ba, bsg, bi, sabs[(wave << 8) + i], ssig[(wave << 8) + i], sidx[(wave << 8) + i]);
#pragma unroll
        for (int m = 32; m >= 1; m >>= 1) {
            float oa = __shfl_xor(ba, m);
            float os = __shfl_xor(bsg, m);
            float oi = __shfl_xor(bi, m);
            cmax(ba, bsg, bi, oa, os, oi);
        }
        if (lane == 0) l2[(b << 8) + (og << 3) + wave] = make_float4(ba, bsg, bi, 0.f);
    }
    __threadfence();
    grid.sync();

    for (int s = 0; s < NSTEP; ++s) {
        // SELECT — computed redundantly (identically) in every block
        {
            float ba = -1.f, bsg = 0.f, bi = 3.0e7f;
            if (tid < 256) {
                float4 e = l2[((s & 1) << 11) + (b << 8) + tid];
                ba = e.x; bsg = e.y; bi = e.z;
            }
#pragma unroll
            for (int m = 32; m >= 1; m >>= 1) {
                float oa = __shfl_xor(ba, m);
                float os = __shfl_xor(bsg, m);
                float oi = __shfl_xor(bi, m);
                cmax(ba, bsg, bi, oa, os, oi);
            }
            if (lane == 0) sred[wave] = make_float4(ba, bsg, bi, 0.f);
        }
        __syncthreads();
        if (tid == 0) {
            float4 r = sred[0];
#pragma unroll
            for (int i = 1; i < 8; ++i) {
                float4 q = sred[i];
                if (q.x > r.x || (q.x == r.x && q.z < r.z)) r = q;
            }
            const int idx = (int)r.z;
            const int atom = idx / TOUT;
            const int pos = idx - atom * TOUT;
            s_pos[s] = pos; s_atom[s] = atom; s_amp[s] = r.y;
            if (og == 0) {
                pos_a[s * BATCH + b] = pos;
                atom_a[s * BATCH + b] = atom;
                amp_a[s * BATCH + b] = r.y;
            }
        }
        __syncthreads();
        if (s == NSTEP - 1) break;

        // UPDATE: rebuild residual window from x + history (exact step order)
        const int p = s_pos[s];
        int tlo = p - 255; if (tlo < 0) tlo = 0;
        int thi = p + 255; if (thi > TOUT - 1) thi = TOUT - 1;
        const int bs0 = tlo >> 7, be0 = thi >> 7;
        const int rbase = bs0 << 7;
        const int nblks = be0 - bs0 + 1;
        const int rlen = (nblks << 7) + 255;
        for (int i = tid; i < rlen; i += 512) {
            const int g = rbase + i;
            float v = (g < NS) ? x[(size_t)b * NS + g] : 0.f;
            for (int s2 = 0; s2 <= s; ++s2) {
                const int off = g - s_pos[s2];
                if (off >= 0 && off < KER)
                    v = __fsub_rn(v, __fmul_rn(s_amp[s2], d[s_atom[s2] * KER + off]));
            }
            rsu[SW4(i)] = v;
        }
        __syncthreads();
        // recompute bm for own 8 atoms over affected blocks; lane-groups split K
        const int lg = lane >> 4, l16 = lane & 15;
        const float* dp = dt + (wave << 8) + (lg << 6);
        const int oglob = (og << 3) + wave;
        for (int bb = 0; bb < nblks; ++bb) {
            const int blk = bs0 + bb;
            const int t0r = (bb << 7) + (l16 << 3) + (lg << 6);
            float acc[8];
#pragma unroll
            for (int j = 0; j < 8; ++j) acc[j] = 0.f;
            float4 A0 = *(const float4*)(rsu + SW4(t0r));
            float4 A1 = *(const float4*)(rsu + SW4(t0r + 4));
            float4 B0 = *(const float4*)(rsu + SW4(t0r + 8));
            float4 B1 = *(const float4*)(rsu + SW4(t0r + 12));
#pragma unroll
            for (int kk = 0; kk < 64; kk += 16) {
                float4 d0 = *(const float4*)(dp + kk);
                float4 d1 = *(const float4*)(dp + kk + 4);
                float4 N0 = *(const float4*)(rsu + SW4(t0r + kk + 16));
                float4 N1 = *(const float4*)(rsu + SW4(t0r + kk + 20));
                fma8(acc, d0, d1, A0, A1, B0, B1);
                float4 d2 = *(const float4*)(dp + kk + 8);
                float4 d3 = *(const float4*)(dp + kk + 12);
                float4 M0 = *(const float4*)(rsu + SW4(t0r + kk + 24));
                float4 M1 = *(const float4*)(rsu + SW4(t0r + kk + 28));
                fma8(acc, d2, d3, B0, B1, N0, N1);
                A0 = N0; A1 = N1; B0 = M0; B1 = M1;
            }
#pragma unroll
            for (int j = 0; j < 8; ++j) {
                acc[j] += __shfl_xor(acc[j], 16);
                acc[j] += __shfl_xor(acc[j], 32);
            }
            float ba = -1.f, bsg = 0.f, bi = 3.0e7f;
            const int tb = rbase + (bb << 7) + (l16 << 3);
#pragma unroll
            for (int j = 0; j < 8; ++j) {
                const int t = tb + j;
                const float av = fabsf(acc[j]);
                if (t < TOUT && av > ba) { ba = av; bsg = acc[j]; bi = (float)(oglob * TOUT + t); }
            }
#pragma unroll
            for (int m = 32; m >= 1; m >>= 1) {
                float oa = __shfl_xor(ba, m);
                float os = __shfl_xor(bsg, m);
                float oi = __shfl_xor(bi, m);
                cmax(ba, bsg, bi, oa, os, oi);
            }
            if (lane == 0) {
                sabs[(wave << 8) + blk] = ba;
                ssig[(wave << 8) + blk] = bsg;
                sidx[(wave << 8) + blk] = bi;
            }
        }
        __syncthreads();
        // refresh level-2 for own atoms into the other l2 buffer
        {
            float ba = -1.f, bsg = 0.f, bi = 3.0e7f;
            for (int i = lane; i < 256; i += 64)
                cmax(ba, bsg, bi, sabs[(wave << 8) + i], ssig[(wave << 8) + i], sidx[(wave << 8) + i]);
#pragma unroll
            for (int m = 32; m >= 1; m >>= 1) {
                float oa = __shfl_xor(ba, m);
                float os = __shfl_xor(bsg, m);
                float oi = __shfl_xor(bi, m);
                cmax(ba, bsg, bi, oa, os, oi);
            }
            if (lane == 0)
                l2[(((s + 1) & 1) << 11) + (b << 8) + (og << 3) + wave] = make_float4(ba, bsg, bi, 0.f);
        }
        __threadfence();
        grid.sync();
    }
}

// Head: out[b,o,s] = br[o] + sum_c wr[o][c]*pa[c] + wr[o][128+c]*at[c]
__global__ __launch_bounds__(128) void k_head(const int* __restrict__ pos_a,
                                              const int* __restrict__ atom_a,
                                              const float* __restrict__ amp_a,
                                              const float* __restrict__ wpa,
                                              const float* __restrict__ bpa,
                                              const float* __restrict__ wat,
                                              const float* __restrict__ bat,
                                              const float* __restrict__ wr,
                                              const float* __restrict__ br,
                                              float* __restrict__ out) {
    const int s = blockIdx.x, b = blockIdx.y;
    const int o = threadIdx.x;
    const int pos = pos_a[s * BATCH + b];
    const int atom = atom_a[s * BATCH + b];
    const float amp = amp_a[s * BATCH + b];
    const float posn = (float)pos / 32513.0f;
    float sum = br[o];
    for (int c = 0; c < 128; ++c) {
        float pa = wpa[c * 2] * posn + wpa[c * 2 + 1] * amp + bpa[c];
        float at = wat[c * 256 + atom] + bat[c];
        sum += wr[o * 256 + c] * pa + wr[o * 256 + 128 + c] * at;
    }
    out[(b * 128 + o) * NSTEP + s] = sum;
}

extern "C" void kernel_launch(void* const* d_in, const int* in_sizes, int n_in,
                              void* d_out, int out_size, void* d_ws, size_t ws_size,
                              hipStream_t stream) {
    const float* x   = (const float*)d_in[0];
    const float* d   = (const float*)d_in[1];
    const float* wpa = (const float*)d_in[2];
    const float* bpa = (const float*)d_in[3];
    const float* wat = (const float*)d_in[4];
    const float* bat = (const float*)d_in[5];
    const float* wr  = (const float*)d_in[6];
    const float* br  = (const float*)d_in[7];
    float* out = (float*)d_out;

    char* ws = (char*)d_ws;
    float4* bm = (float4*)ws;                              // 8*256*255*16 = 8,355,840 B
    float4* l2 = (float4*)(ws + 8355840);                  // 2*2048*16 = 65,536 B
    int*   pos_a  = (int*)(ws + 8355840 + 65536);
    int*   atom_a = pos_a + NSTEP * BATCH;
    float* amp_a  = (float*)(atom_a + NSTEP * BATCH);

    k_init<<<dim3(8, 16, 8), 256, 0, stream>>>(x, d, bm);
    void* args[] = {(void*)&x, (void*)&d, (void*)&bm, (void*)&l2,
                    (void*)&pos_a, (void*)&atom_a, (void*)&amp_a};
    hipLaunchCooperativeKernel((const void*)k_iter, dim3(32, 8), dim3(512),
                               args, 0, stream);
    k_head<<<dim3(16, 8), 128, 0, stream>>>(pos_a, atom_a, amp_a,
                                            wpa, bpa, wat, bat, wr, br, out);
}

// Round 3
// 1844.010 us; speedup vs baseline: 1.0256x; 1.0256x over previous
//
#include <hip/hip_runtime.h>
#include <hip/hip_bf16.h>
#include <float.h>

#define NS 32768
#define KER 256
#define TOUT 32513
#define NATOM 256
#define NSTEP 16
#define BATCH 8
#define NBLK 255
#define SW4(i) ((i) + (((i) >> 5) << 2))

__device__ __forceinline__ void cmax(float& ba, float& bs, float& bi,
                                     float oa, float os, float oi) {
    if (oa > ba || (oa == ba && oi < bi)) { ba = oa; bs = os; bi = oi; }
}

__device__ __forceinline__ void fma16(float acc[16], float4 dA, float4 dB,
                                      float4 q0, float4 q1, float4 q2,
                                      float4 q3, float4 q4, float4 q5) {
    float w[24] = {q0.x,q0.y,q0.z,q0.w, q1.x,q1.y,q1.z,q1.w,
                   q2.x,q2.y,q2.z,q2.w, q3.x,q3.y,q3.z,q3.w,
                   q4.x,q4.y,q4.z,q4.w, q5.x,q5.y,q5.z,q5.w};
    float dv[8] = {dA.x,dA.y,dA.z,dA.w, dB.x,dB.y,dB.z,dB.w};
#pragma unroll
    for (int i = 0; i < 8; ++i)
#pragma unroll
        for (int j = 0; j < 16; ++j)
            acc[j] = fmaf(dv[i], w[i + j], acc[j]);
}

__device__ __forceinline__ void fma8(float acc[8], float4 dA, float4 dB,
                                     float4 w0, float4 w1, float4 w2, float4 w3) {
    float w[16] = {w0.x,w0.y,w0.z,w0.w, w1.x,w1.y,w1.z,w1.w,
                   w2.x,w2.y,w2.z,w2.w, w3.x,w3.y,w3.z,w3.w};
    float dv[8] = {dA.x,dA.y,dA.z,dA.w, dB.x,dB.y,dB.z,dB.w};
#pragma unroll
    for (int i = 0; i < 8; ++i)
#pragma unroll
        for (int j = 0; j < 8; ++j)
            acc[j] = fmaf(dv[i], w[i + j], acc[j]);
}

// Full correlation of x with all 256 atoms + per-128-block abs-argmax.
// grid: (8 t-chunks of 4096, 32 atom-groups of 8, 8 batch), block 256.
// Atom-PAIRED inner loop: each LDS window read feeds 2 atoms' FMAs.
__global__ __launch_bounds__(256, 4) void k_init(const float* __restrict__ x,
                                                 const float* __restrict__ d,
                                                 float4* __restrict__ bm) {
    const int c = blockIdx.x, og = blockIdx.y, b = blockIdx.z;
    const int tid = threadIdx.x;
    __shared__ float rs[4896];   // SW4-swizzled, covers idx 0..4351
    __shared__ float dt[2048];   // 8 atoms x 256
    const int base = c * 4096;
    const float* xp = x + (size_t)b * NS;
    for (int i4 = tid; i4 < 1088; i4 += 256) {
        const int i = i4 << 2, g = base + i;
        float4 v;
        if (g + 3 < NS) v = *(const float4*)(xp + g);
        else {
            v.x = (g     < NS) ? xp[g]     : 0.f;
            v.y = (g + 1 < NS) ? xp[g + 1] : 0.f;
            v.z = (g + 2 < NS) ? xp[g + 2] : 0.f;
            v.w = (g + 3 < NS) ? xp[g + 3] : 0.f;
        }
        *(float4*)(rs + SW4(i)) = v;
    }
    {
        const float4* ds4 = (const float4*)(d + og * 2048);
        float4* dd4 = (float4*)dt;
        dd4[tid] = ds4[tid];
        dd4[tid + 256] = ds4[tid + 256];
    }
    __syncthreads();
    const int t0 = tid << 4;

#define ARGMAX_STORE(ACC, OGLOB)                                                 \
    do {                                                                         \
        float ba = -1.f, bsg = 0.f, bi = 3.0e7f;                                 \
        _Pragma("unroll")                                                        \
        for (int j = 0; j < 16; ++j) {                                           \
            const int t = base + t0 + j;                                         \
            const float av = fabsf(ACC[j]);                                      \
            if (t < TOUT && av > ba) { ba = av; bsg = ACC[j];                    \
                                       bi = (float)((OGLOB) * TOUT + t); }       \
        }                                                                        \
        _Pragma("unroll")                                                        \
        for (int m = 4; m >= 1; m >>= 1) {                                       \
            float oa = __shfl_xor(ba, m, 8);                                     \
            float os = __shfl_xor(bsg, m, 8);                                    \
            float oi = __shfl_xor(bi, m, 8);                                     \
            cmax(ba, bsg, bi, oa, os, oi);                                       \
        }                                                                        \
        if ((tid & 7) == 0) {                                                    \
            const int blk = (c << 5) + (tid >> 3);                               \
            if (blk < NBLK)                                                      \
                bm[(size_t)(b * NATOM + (OGLOB)) * NBLK + blk] =                 \
                    make_float4(ba, bsg, bi, 0.f);                               \
        }                                                                        \
    } while (0)

    for (int pp = 0; pp < 4; ++pp) {
        const float* dr0 = dt + (pp << 9);
        const float* dr1 = dr0 + 256;
        float acc0[16], acc1[16];
#pragma unroll
        for (int j = 0; j < 16; ++j) { acc0[j] = 0.f; acc1[j] = 0.f; }
        float4 Q0 = *(const float4*)(rs + SW4(t0));
        float4 Q1 = *(const float4*)(rs + SW4(t0 + 4));
        float4 Q2 = *(const float4*)(rs + SW4(t0 + 8));
        float4 Q3 = *(const float4*)(rs + SW4(t0 + 12));
#pragma unroll
        for (int kk = 0; kk < 256; kk += 16) {
            float4 Q4 = *(const float4*)(rs + SW4(t0 + kk + 16));
            float4 Q5 = *(const float4*)(rs + SW4(t0 + kk + 20));
            fma16(acc0, *(const float4*)(dr0 + kk), *(const float4*)(dr0 + kk + 4),
                  Q0, Q1, Q2, Q3, Q4, Q5);
            fma16(acc1, *(const float4*)(dr1 + kk), *(const float4*)(dr1 + kk + 4),
                  Q0, Q1, Q2, Q3, Q4, Q5);
            float4 P0 = *(const float4*)(rs + SW4(t0 + kk + 24));
            float4 P1 = *(const float4*)(rs + SW4(t0 + kk + 28));
            fma16(acc0, *(const float4*)(dr0 + kk + 8), *(const float4*)(dr0 + kk + 12),
                  Q2, Q3, Q4, Q5, P0, P1);
            fma16(acc1, *(const float4*)(dr1 + kk + 8), *(const float4*)(dr1 + kk + 12),
                  Q2, Q3, Q4, Q5, P0, P1);
            Q0 = Q4; Q1 = Q5; Q2 = P0; Q3 = P1;
        }
        const int oglob0 = (og << 3) + (pp << 1);
        ARGMAX_STORE(acc0, oglob0);
        ARGMAX_STORE(acc1, oglob0 + 1);
    }
#undef ARGMAX_STORE
}

// Per-atom (level-2) maxima over all blocks -> l2 buffer 0.
// grid (32 groups of 8 atoms, 8 b), block 256
__global__ __launch_bounds__(256) void k_lvl2(const float4* __restrict__ bm,
                                              float4* __restrict__ l2) {
    const int b = blockIdx.y;
    const int oglob = blockIdx.x * 8 + (threadIdx.x >> 5);
    const int lane = threadIdx.x & 31;
    const float4* row = bm + (size_t)(b * NATOM + oglob) * NBLK;
    float ba = -1.f, bsg = 0.f, bi = 3.0e7f;
    for (int i = lane; i < NBLK; i += 32) {
        float4 e = row[i];
        cmax(ba, bsg, bi, e.x, e.y, e.z);
    }
#pragma unroll
    for (int m = 16; m >= 1; m >>= 1) {
        float oa = __shfl_xor(ba, m, 32);
        float os = __shfl_xor(bsg, m, 32);
        float oi = __shfl_xor(bi, m, 32);
        cmax(ba, bsg, bi, oa, os, oi);
    }
    if (lane == 0) l2[(b << 8) + oglob] = make_float4(ba, bsg, bi, 0.f);
}

// One MP step: redundant select(step) per block + window update of own 8 atoms.
// l2 is parity double-buffered: read buf[step&1], write buf[(step+1)&1].
// grid (32 atom-groups of 8, 8 b), block 512 (8 waves, wave w -> atom w).
__global__ __launch_bounds__(512) void k_step(const float* __restrict__ x,
                                              const float* __restrict__ d,
                                              float4* __restrict__ bm,
                                              float4* __restrict__ l2,
                                              int* __restrict__ pos_a,
                                              int* __restrict__ atom_a,
                                              float* __restrict__ amp_a,
                                              int step) {
    const int og = blockIdx.x, b = blockIdx.y;
    const int tid = threadIdx.x;
    const int wave = tid >> 6, lane = tid & 63;
    __shared__ float dt[2048];
    __shared__ float rsu[1024];
    __shared__ float4 sred[8];
    __shared__ float4 upd[8][5];
    __shared__ int s_pos[NSTEP], s_atom[NSTEP];
    __shared__ float s_amp[NSTEP];

    ((float4*)dt)[tid] = ((const float4*)(d + og * 2048))[tid];
    if (tid < step) {
        s_pos[tid]  = pos_a[tid * BATCH + b];
        s_atom[tid] = atom_a[tid * BATCH + b];
        s_amp[tid]  = amp_a[tid * BATCH + b];
    }
    const float4* l2r = l2 + (step & 1) * (BATCH * NATOM);
    float4*       l2w = l2 + ((step + 1) & 1) * (BATCH * NATOM);

    // SELECT(step) — identical in every block
    {
        float ba = -1.f, bsg = 0.f, bi = 3.0e7f;
        if (tid < 256) {
            float4 e = l2r[(b << 8) + tid];
            ba = e.x; bsg = e.y; bi = e.z;
        }
#pragma unroll
        for (int m = 32; m >= 1; m >>= 1) {
            float oa = __shfl_xor(ba, m);
            float os = __shfl_xor(bsg, m);
            float oi = __shfl_xor(bi, m);
            cmax(ba, bsg, bi, oa, os, oi);
        }
        if (lane == 0) sred[wave] = make_float4(ba, bsg, bi, 0.f);
    }
    __syncthreads();
    if (tid == 0) {
        float4 r = sred[0];
#pragma unroll
        for (int i = 1; i < 8; ++i) {
            float4 q = sred[i];
            if (q.x > r.x || (q.x == r.x && q.z < r.z)) r = q;
        }
        const int idx = (int)r.z;
        const int atom = idx / TOUT;
        const int pos = idx - atom * TOUT;
        s_pos[step] = pos; s_atom[step] = atom; s_amp[step] = r.y;
        if (og == 0) {
            pos_a[step * BATCH + b] = pos;
            atom_a[step * BATCH + b] = atom;
            amp_a[step * BATCH + b] = r.y;
        }
    }
    __syncthreads();

    // Rebuild residual window from x + full history (reference step order)
    const int p = s_pos[step];
    int tlo = p - 255; if (tlo < 0) tlo = 0;
    int thi = p + 255; if (thi > TOUT - 1) thi = TOUT - 1;
    const int bs0 = tlo >> 7, be0 = thi >> 7;
    const int rbase = bs0 << 7;
    const int nblks = be0 - bs0 + 1;
    const int rlen = (nblks << 7) + 255;
    for (int i = tid; i < rlen; i += 512) {
        const int g = rbase + i;
        float v = (g < NS) ? x[(size_t)b * NS + g] : 0.f;
        for (int s2 = 0; s2 <= step; ++s2) {
            const int off = g - s_pos[s2];
            if (off >= 0 && off < KER)
                v = __fsub_rn(v, __fmul_rn(s_amp[s2], d[s_atom[s2] * KER + off]));
        }
        rsu[SW4(i)] = v;
    }
    __syncthreads();

    // Recompute bm for own 8 atoms over affected blocks (4-way K-split per wave)
    const int lg = lane >> 4, l16 = lane & 15;
    const float* dp = dt + (wave << 8) + (lg << 6);
    const int atomg = (og << 3) + wave;
    for (int bb = 0; bb < nblks; ++bb) {
        const int blk = bs0 + bb;
        const int t0r = (bb << 7) + (l16 << 3) + (lg << 6);
        float acc[8];
#pragma unroll
        for (int j = 0; j < 8; ++j) acc[j] = 0.f;
        float4 A0 = *(const float4*)(rsu + SW4(t0r));
        float4 A1 = *(const float4*)(rsu + SW4(t0r + 4));
        float4 B0 = *(const float4*)(rsu + SW4(t0r + 8));
        float4 B1 = *(const float4*)(rsu + SW4(t0r + 12));
#pragma unroll
        for (int kk = 0; kk < 64; kk += 16) {
            float4 d0 = *(const float4*)(dp + kk);
            float4 d1 = *(const float4*)(dp + kk + 4);
            float4 N0 = *(const float4*)(rsu + SW4(t0r + kk + 16));
            float4 N1 = *(const float4*)(rsu + SW4(t0r + kk + 20));
            fma8(acc, d0, d1, A0, A1, B0, B1);
            float4 d2 = *(const float4*)(dp + kk + 8);
            float4 d3 = *(const float4*)(dp + kk + 12);
            float4 M0 = *(const float4*)(rsu + SW4(t0r + kk + 24));
            float4 M1 = *(const float4*)(rsu + SW4(t0r + kk + 28));
            fma8(acc, d2, d3, B0, B1, N0, N1);
            A0 = N0; A1 = N1; B0 = M0; B1 = M1;
        }
#pragma unroll
        for (int j = 0; j < 8; ++j) {
            acc[j] += __shfl_xor(acc[j], 16);
            acc[j] += __shfl_xor(acc[j], 32);
        }
        float ba = -1.f, bsg = 0.f, bi = 3.0e7f;
        const int tb = rbase + (bb << 7) + (l16 << 3);
#pragma unroll
        for (int j = 0; j < 8; ++j) {
            const int t = tb + j;
            const float av = fabsf(acc[j]);
            if (t < TOUT && av > ba) { ba = av; bsg = acc[j]; bi = (float)(atomg * TOUT + t); }
        }
#pragma unroll
        for (int m = 32; m >= 1; m >>= 1) {
            float oa = __shfl_xor(ba, m);
            float os = __shfl_xor(bsg, m);
            float oi = __shfl_xor(bi, m);
            cmax(ba, bsg, bi, oa, os, oi);
        }
        if (lane == 0) {
            float4 e4 = make_float4(ba, bsg, bi, 0.f);
            bm[(size_t)(b * NATOM + atomg) * NBLK + blk] = e4;
            upd[wave][bb] = e4;
        }
    }
    __syncthreads();

    // l2 refresh (global row, LDS-override for just-updated blocks)
    {
        float ba = -1.f, bsg = 0.f, bi = 3.0e7f;
        const float4* row = bm + (size_t)(b * NATOM + atomg) * NBLK;
        for (int i = lane; i < NBLK; i += 64) {
            float4 e2 = (i >= bs0 && i <= be0) ? upd[wave][i - bs0] : row[i];
            cmax(ba, bsg, bi, e2.x, e2.y, e2.z);
        }
#pragma unroll
        for (int m = 32; m >= 1; m >>= 1) {
            float oa = __shfl_xor(ba, m);
            float os = __shfl_xor(bsg, m);
            float oi = __shfl_xor(bi, m);
            cmax(ba, bsg, bi, oa, os, oi);
        }
        if (lane == 0) l2w[(b << 8) + atomg] = make_float4(ba, bsg, bi, 0.f);
    }
}

// Head; blocks with s==15 compute the final select inline from l2 buf1.
__global__ __launch_bounds__(128) void k_head(const int* __restrict__ pos_a,
                                              const int* __restrict__ atom_a,
                                              const float* __restrict__ amp_a,
                                              const float4* __restrict__ l2,
                                              const float* __restrict__ wpa,
                                              const float* __restrict__ bpa,
                                              const float* __restrict__ wat,
                                              const float* __restrict__ bat,
                                              const float* __restrict__ wr,
                                              const float* __restrict__ br,
                                              float* __restrict__ out) {
    const int s = blockIdx.x, b = blockIdx.y;
    const int o = threadIdx.x;
    __shared__ float4 hred[2];
    __shared__ int sh_pos, sh_atom;
    __shared__ float sh_amp;
    int pos, atom; float amp;
    if (s == NSTEP - 1) {
        const float4* l2r = l2 + ((NSTEP - 1) & 1) * (BATCH * NATOM);
        float ba = -1.f, bsg = 0.f, bi = 3.0e7f;
        float4 e0 = l2r[(b << 8) + o];
        float4 e1 = l2r[(b << 8) + 128 + o];
        cmax(ba, bsg, bi, e0.x, e0.y, e0.z);
        cmax(ba, bsg, bi, e1.x, e1.y, e1.z);
#pragma unroll
        for (int m = 32; m >= 1; m >>= 1) {
            float oa = __shfl_xor(ba, m);
            float os = __shfl_xor(bsg, m);
            float oi = __shfl_xor(bi, m);
            cmax(ba, bsg, bi, oa, os, oi);
        }
        if ((o & 63) == 0) hred[o >> 6] = make_float4(ba, bsg, bi, 0.f);
        __syncthreads();
        if (o == 0) {
            float4 r = hred[0], q = hred[1];
            if (q.x > r.x || (q.x == r.x && q.z < r.z)) r = q;
            const int idx = (int)r.z;
            sh_atom = idx / TOUT;
            sh_pos = idx - sh_atom * TOUT;
            sh_amp = r.y;
        }
        __syncthreads();
        pos = sh_pos; atom = sh_atom; amp = sh_amp;
    } else {
        pos  = pos_a[s * BATCH + b];
        atom = atom_a[s * BATCH + b];
        amp  = amp_a[s * BATCH + b];
    }
    const float posn = (float)pos / 32513.0f;
    float sum = br[o];
    for (int c = 0; c < 128; ++c) {
        float pa = wpa[c * 2] * posn + wpa[c * 2 + 1] * amp + bpa[c];
        float at = wat[c * 256 + atom] + bat[c];
        sum += wr[o * 256 + c] * pa + wr[o * 256 + 128 + c] * at;
    }
    out[(b * 128 + o) * NSTEP + s] = sum;
}

extern "C" void kernel_launch(void* const* d_in, const int* in_sizes, int n_in,
                              void* d_out, int out_size, void* d_ws, size_t ws_size,
                              hipStream_t stream) {
    const float* x   = (const float*)d_in[0];
    const float* d   = (const float*)d_in[1];
    const float* wpa = (const float*)d_in[2];
    const float* bpa = (const float*)d_in[3];
    const float* wat = (const float*)d_in[4];
    const float* bat = (const float*)d_in[5];
    const float* wr  = (const float*)d_in[6];
    const float* br  = (const float*)d_in[7];
    float* out = (float*)d_out;

    char* ws = (char*)d_ws;
    float4* bm = (float4*)ws;                          // 8*256*255*16 = 8,355,840 B
    float4* l2 = (float4*)(ws + 8355840);              // 2*2048*16 = 65,536 B
    int*   pos_a  = (int*)(ws + 8355840 + 65536);
    int*   atom_a = pos_a + NSTEP * BATCH;
    float* amp_a  = (float*)(atom_a + NSTEP * BATCH);

    k_init<<<dim3(8, 32, 8), 256, 0, stream>>>(x, d, bm);
    k_lvl2<<<dim3(32, 8), 256, 0, stream>>>(bm, l2);
    for (int st = 0; st < NSTEP - 1; ++st)
        k_step<<<dim3(32, 8), 512, 0, stream>>>(x, d, bm, l2, pos_a, atom_a, amp_a, st);
    k_head<<<dim3(16, 8), 128, 0, stream>>>(pos_a, atom_a, amp_a, l2,
                                            wpa, bpa, wat, bat, wr, br, out);
}

// Round 4
// 880.900 us; speedup vs baseline: 2.1469x; 2.0933x over previous
//
#include <hip/hip_runtime.h>
#include <hip/hip_bf16.h>
#include <float.h>

#define NS 32768
#define KER 256
#define TOUT 32513
#define NATOM 256
#define NSTEP 16
#define BATCH 8
#define NBLK 255
#define SW4(i) ((i) + (((i) >> 5) << 2))

__device__ __forceinline__ void cmax(float& ba, float& bs, float& bi,
                                     float oa, float os, float oi) {
    if (oa > ba || (oa == ba && oi < bi)) { ba = oa; bs = os; bi = oi; }
}

__device__ __forceinline__ void fma16(float acc[16], float4 dA, float4 dB,
                                      float4 q0, float4 q1, float4 q2,
                                      float4 q3, float4 q4, float4 q5) {
    float w[24] = {q0.x,q0.y,q0.z,q0.w, q1.x,q1.y,q1.z,q1.w,
                   q2.x,q2.y,q2.z,q2.w, q3.x,q3.y,q3.z,q3.w,
                   q4.x,q4.y,q4.z,q4.w, q5.x,q5.y,q5.z,q5.w};
    float dv[8] = {dA.x,dA.y,dA.z,dA.w, dB.x,dB.y,dB.z,dB.w};
#pragma unroll
    for (int i = 0; i < 8; ++i)
#pragma unroll
        for (int j = 0; j < 16; ++j)
            acc[j] = fmaf(dv[i], w[i + j], acc[j]);
}

__device__ __forceinline__ void fma8(float acc[8], float4 dA, float4 dB,
                                     float4 w0, float4 w1, float4 w2, float4 w3) {
    float w[16] = {w0.x,w0.y,w0.z,w0.w, w1.x,w1.y,w1.z,w1.w,
                   w2.x,w2.y,w2.z,w2.w, w3.x,w3.y,w3.z,w3.w};
    float dv[8] = {dA.x,dA.y,dA.z,dA.w, dB.x,dB.y,dB.z,dB.w};
#pragma unroll
    for (int i = 0; i < 8; ++i)
#pragma unroll
        for (int j = 0; j < 8; ++j)
            acc[j] = fmaf(dv[i], w[i + j], acc[j]);
}

// Full correlation of x with all 256 atoms + per-128-block abs-argmax.
// grid: (8 t-chunks of 4096, 32 atom-groups of 8, 8 batch), block 256.
// Atom-PAIRED inner loop: each LDS window read feeds 2 atoms' FMAs.
// NOTE: no min-waves clamp — r3's (256,4) forced VGPR=64 and spilled
// ~4.8 GB of scratch traffic to HBM (FETCH 2.7 GB). Let VGPR float to ~120.
__global__ __launch_bounds__(256) void k_init(const float* __restrict__ x,
                                              const float* __restrict__ d,
                                              float4* __restrict__ bm) {
    const int c = blockIdx.x, og = blockIdx.y, b = blockIdx.z;
    const int tid = threadIdx.x;
    __shared__ float rs[4896];   // SW4-swizzled, covers idx 0..4351
    __shared__ float dt[2048];   // 8 atoms x 256
    const int base = c * 4096;
    const float* xp = x + (size_t)b * NS;
    for (int i4 = tid; i4 < 1088; i4 += 256) {
        const int i = i4 << 2, g = base + i;
        float4 v;
        if (g + 3 < NS) v = *(const float4*)(xp + g);
        else {
            v.x = (g     < NS) ? xp[g]     : 0.f;
            v.y = (g + 1 < NS) ? xp[g + 1] : 0.f;
            v.z = (g + 2 < NS) ? xp[g + 2] : 0.f;
            v.w = (g + 3 < NS) ? xp[g + 3] : 0.f;
        }
        *(float4*)(rs + SW4(i)) = v;
    }
    {
        const float4* ds4 = (const float4*)(d + og * 2048);
        float4* dd4 = (float4*)dt;
        dd4[tid] = ds4[tid];
        dd4[tid + 256] = ds4[tid + 256];
    }
    __syncthreads();
    const int t0 = tid << 4;

#define ARGMAX_STORE(ACC, OGLOB)                                                 \
    do {                                                                         \
        float ba = -1.f, bsg = 0.f, bi = 3.0e7f;                                 \
        _Pragma("unroll")                                                        \
        for (int j = 0; j < 16; ++j) {                                           \
            const int t = base + t0 + j;                                         \
            const float av = fabsf(ACC[j]);                                      \
            if (t < TOUT && av > ba) { ba = av; bsg = ACC[j];                    \
                                       bi = (float)((OGLOB) * TOUT + t); }       \
        }                                                                        \
        _Pragma("unroll")                                                        \
        for (int m = 4; m >= 1; m >>= 1) {                                       \
            float oa = __shfl_xor(ba, m, 8);                                     \
            float os = __shfl_xor(bsg, m, 8);                                    \
            float oi = __shfl_xor(bi, m, 8);                                     \
            cmax(ba, bsg, bi, oa, os, oi);                                       \
        }                                                                        \
        if ((tid & 7) == 0) {                                                    \
            const int blk = (c << 5) + (tid >> 3);                               \
            if (blk < NBLK)                                                      \
                bm[(size_t)(b * NATOM + (OGLOB)) * NBLK + blk] =                 \
                    make_float4(ba, bsg, bi, 0.f);                               \
        }                                                                        \
    } while (0)

    for (int pp = 0; pp < 4; ++pp) {
        const float* dr0 = dt + (pp << 9);
        const float* dr1 = dr0 + 256;
        float acc0[16], acc1[16];
#pragma unroll
        for (int j = 0; j < 16; ++j) { acc0[j] = 0.f; acc1[j] = 0.f; }
        float4 Q0 = *(const float4*)(rs + SW4(t0));
        float4 Q1 = *(const float4*)(rs + SW4(t0 + 4));
        float4 Q2 = *(const float4*)(rs + SW4(t0 + 8));
        float4 Q3 = *(const float4*)(rs + SW4(t0 + 12));
#pragma unroll
        for (int kk = 0; kk < 256; kk += 16) {
            float4 Q4 = *(const float4*)(rs + SW4(t0 + kk + 16));
            float4 Q5 = *(const float4*)(rs + SW4(t0 + kk + 20));
            fma16(acc0, *(const float4*)(dr0 + kk), *(const float4*)(dr0 + kk + 4),
                  Q0, Q1, Q2, Q3, Q4, Q5);
            fma16(acc1, *(const float4*)(dr1 + kk), *(const float4*)(dr1 + kk + 4),
                  Q0, Q1, Q2, Q3, Q4, Q5);
            float4 P0 = *(const float4*)(rs + SW4(t0 + kk + 24));
            float4 P1 = *(const float4*)(rs + SW4(t0 + kk + 28));
            fma16(acc0, *(const float4*)(dr0 + kk + 8), *(const float4*)(dr0 + kk + 12),
                  Q2, Q3, Q4, Q5, P0, P1);
            fma16(acc1, *(const float4*)(dr1 + kk + 8), *(const float4*)(dr1 + kk + 12),
                  Q2, Q3, Q4, Q5, P0, P1);
            Q0 = Q4; Q1 = Q5; Q2 = P0; Q3 = P1;
        }
        const int oglob0 = (og << 3) + (pp << 1);
        ARGMAX_STORE(acc0, oglob0);
        ARGMAX_STORE(acc1, oglob0 + 1);
    }
#undef ARGMAX_STORE
}

// Per-atom (level-2) maxima over all blocks -> l2 buffer 0.
// grid (32 groups of 8 atoms, 8 b), block 256
__global__ __launch_bounds__(256) void k_lvl2(const float4* __restrict__ bm,
                                              float4* __restrict__ l2) {
    const int b = blockIdx.y;
    const int oglob = blockIdx.x * 8 + (threadIdx.x >> 5);
    const int lane = threadIdx.x & 31;
    const float4* row = bm + (size_t)(b * NATOM + oglob) * NBLK;
    float ba = -1.f, bsg = 0.f, bi = 3.0e7f;
    for (int i = lane; i < NBLK; i += 32) {
        float4 e = row[i];
        cmax(ba, bsg, bi, e.x, e.y, e.z);
    }
#pragma unroll
    for (int m = 16; m >= 1; m >>= 1) {
        float oa = __shfl_xor(ba, m, 32);
        float os = __shfl_xor(bsg, m, 32);
        float oi = __shfl_xor(bi, m, 32);
        cmax(ba, bsg, bi, oa, os, oi);
    }
    if (lane == 0) l2[(b << 8) + oglob] = make_float4(ba, bsg, bi, 0.f);
}

// One MP step: redundant select(step) per block + window update of own 8 atoms.
// l2 is parity double-buffered: read buf[step&1], write buf[(step+1)&1].
// grid (32 atom-groups of 8, 8 b), block 512 (8 waves, wave w -> atom w).
__global__ __launch_bounds__(512) void k_step(const float* __restrict__ x,
                                              const float* __restrict__ d,
                                              float4* __restrict__ bm,
                                              float4* __restrict__ l2,
                                              int* __restrict__ pos_a,
                                              int* __restrict__ atom_a,
                                              float* __restrict__ amp_a,
                                              int step) {
    const int og = blockIdx.x, b = blockIdx.y;
    const int tid = threadIdx.x;
    const int wave = tid >> 6, lane = tid & 63;
    __shared__ float dt[2048];
    __shared__ float rsu[1024];
    __shared__ float4 sred[8];
    __shared__ float4 upd[8][5];
    __shared__ int s_pos[NSTEP], s_atom[NSTEP];
    __shared__ float s_amp[NSTEP];

    ((float4*)dt)[tid] = ((const float4*)(d + og * 2048))[tid];
    if (tid < step) {
        s_pos[tid]  = pos_a[tid * BATCH + b];
        s_atom[tid] = atom_a[tid * BATCH + b];
        s_amp[tid]  = amp_a[tid * BATCH + b];
    }
    const float4* l2r = l2 + (step & 1) * (BATCH * NATOM);
    float4*       l2w = l2 + ((step + 1) & 1) * (BATCH * NATOM);

    // SELECT(step) — identical in every block
    {
        float ba = -1.f, bsg = 0.f, bi = 3.0e7f;
        if (tid < 256) {
            float4 e = l2r[(b << 8) + tid];
            ba = e.x; bsg = e.y; bi = e.z;
        }
#pragma unroll
        for (int m = 32; m >= 1; m >>= 1) {
            float oa = __shfl_xor(ba, m);
            float os = __shfl_xor(bsg, m);
            float oi = __shfl_xor(bi, m);
            cmax(ba, bsg, bi, oa, os, oi);
        }
        if (lane == 0) sred[wave] = make_float4(ba, bsg, bi, 0.f);
    }
    __syncthreads();
    if (tid == 0) {
        float4 r = sred[0];
#pragma unroll
        for (int i = 1; i < 8; ++i) {
            float4 q = sred[i];
            if (q.x > r.x || (q.x == r.x && q.z < r.z)) r = q;
        }
        const int idx = (int)r.z;
        const int atom = idx / TOUT;
        const int pos = idx - atom * TOUT;
        s_pos[step] = pos; s_atom[step] = atom; s_amp[step] = r.y;
        if (og == 0) {
            pos_a[step * BATCH + b] = pos;
            atom_a[step * BATCH + b] = atom;
            amp_a[step * BATCH + b] = r.y;
        }
    }
    __syncthreads();

    // Rebuild residual window from x + full history (reference step order)
    const int p = s_pos[step];
    int tlo = p - 255; if (tlo < 0) tlo = 0;
    int thi = p + 255; if (thi > TOUT - 1) thi = TOUT - 1;
    const int bs0 = tlo >> 7, be0 = thi >> 7;
    const int rbase = bs0 << 7;
    const int nblks = be0 - bs0 + 1;
    const int rlen = (nblks << 7) + 255;
    for (int i = tid; i < rlen; i += 512) {
        const int g = rbase + i;
        float v = (g < NS) ? x[(size_t)b * NS + g] : 0.f;
        for (int s2 = 0; s2 <= step; ++s2) {
            const int off = g - s_pos[s2];
            if (off >= 0 && off < KER)
                v = __fsub_rn(v, __fmul_rn(s_amp[s2], d[s_atom[s2] * KER + off]));
        }
        rsu[SW4(i)] = v;
    }
    __syncthreads();

    // Recompute bm for own 8 atoms over affected blocks (4-way K-split per wave)
    const int lg = lane >> 4, l16 = lane & 15;
    const float* dp = dt + (wave << 8) + (lg << 6);
    const int atomg = (og << 3) + wave;
    for (int bb = 0; bb < nblks; ++bb) {
        const int blk = bs0 + bb;
        const int t0r = (bb << 7) + (l16 << 3) + (lg << 6);
        float acc[8];
#pragma unroll
        for (int j = 0; j < 8; ++j) acc[j] = 0.f;
        float4 A0 = *(const float4*)(rsu + SW4(t0r));
        float4 A1 = *(const float4*)(rsu + SW4(t0r + 4));
        float4 B0 = *(const float4*)(rsu + SW4(t0r + 8));
        float4 B1 = *(const float4*)(rsu + SW4(t0r + 12));
#pragma unroll
        for (int kk = 0; kk < 64; kk += 16) {
            float4 d0 = *(const float4*)(dp + kk);
            float4 d1 = *(const float4*)(dp + kk + 4);
            float4 N0 = *(const float4*)(rsu + SW4(t0r + kk + 16));
            float4 N1 = *(const float4*)(rsu + SW4(t0r + kk + 20));
            fma8(acc, d0, d1, A0, A1, B0, B1);
            float4 d2 = *(const float4*)(dp + kk + 8);
            float4 d3 = *(const float4*)(dp + kk + 12);
            float4 M0 = *(const float4*)(rsu + SW4(t0r + kk + 24));
            float4 M1 = *(const float4*)(rsu + SW4(t0r + kk + 28));
            fma8(acc, d2, d3, B0, B1, N0, N1);
            A0 = N0; A1 = N1; B0 = M0; B1 = M1;
        }
#pragma unroll
        for (int j = 0; j < 8; ++j) {
            acc[j] += __shfl_xor(acc[j], 16);
            acc[j] += __shfl_xor(acc[j], 32);
        }
        float ba = -1.f, bsg = 0.f, bi = 3.0e7f;
        const int tb = rbase + (bb << 7) + (l16 << 3);
#pragma unroll
        for (int j = 0; j < 8; ++j) {
            const int t = tb + j;
            const float av = fabsf(acc[j]);
            if (t < TOUT && av > ba) { ba = av; bsg = acc[j]; bi = (float)(atomg * TOUT + t); }
        }
#pragma unroll
        for (int m = 32; m >= 1; m >>= 1) {
            float oa = __shfl_xor(ba, m);
            float os = __shfl_xor(bsg, m);
            float oi = __shfl_xor(bi, m);
            cmax(ba, bsg, bi, oa, os, oi);
        }
        if (lane == 0) {
            float4 e4 = make_float4(ba, bsg, bi, 0.f);
            bm[(size_t)(b * NATOM + atomg) * NBLK + blk] = e4;
            upd[wave][bb] = e4;
        }
    }
    __syncthreads();

    // l2 refresh (global row, LDS-override for just-updated blocks)
    {
        float ba = -1.f, bsg = 0.f, bi = 3.0e7f;
        const float4* row = bm + (size_t)(b * NATOM + atomg) * NBLK;
        for (int i = lane; i < NBLK; i += 64) {
            float4 e2 = (i >= bs0 && i <= be0) ? upd[wave][i - bs0] : row[i];
            cmax(ba, bsg, bi, e2.x, e2.y, e2.z);
        }
#pragma unroll
        for (int m = 32; m >= 1; m >>= 1) {
            float oa = __shfl_xor(ba, m);
            float os = __shfl_xor(bsg, m);
            float oi = __shfl_xor(bi, m);
            cmax(ba, bsg, bi, oa, os, oi);
        }
        if (lane == 0) l2w[(b << 8) + atomg] = make_float4(ba, bsg, bi, 0.f);
    }
}

// Head; blocks with s==15 compute the final select inline from l2 buf1.
__global__ __launch_bounds__(128) void k_head(const int* __restrict__ pos_a,
                                              const int* __restrict__ atom_a,
                                              const float* __restrict__ amp_a,
                                              const float4* __restrict__ l2,
                                              const float* __restrict__ wpa,
                                              const float* __restrict__ bpa,
                                              const float* __restrict__ wat,
                                              const float* __restrict__ bat,
                                              const float* __restrict__ wr,
                                              const float* __restrict__ br,
                                              float* __restrict__ out) {
    const int s = blockIdx.x, b = blockIdx.y;
    const int o = threadIdx.x;
    __shared__ float4 hred[2];
    __shared__ int sh_pos, sh_atom;
    __shared__ float sh_amp;
    int pos, atom; float amp;
    if (s == NSTEP - 1) {
        const float4* l2r = l2 + ((NSTEP - 1) & 1) * (BATCH * NATOM);
        float ba = -1.f, bsg = 0.f, bi = 3.0e7f;
        float4 e0 = l2r[(b << 8) + o];
        float4 e1 = l2r[(b << 8) + 128 + o];
        cmax(ba, bsg, bi, e0.x, e0.y, e0.z);
        cmax(ba, bsg, bi, e1.x, e1.y, e1.z);
#pragma unroll
        for (int m = 32; m >= 1; m >>= 1) {
            float oa = __shfl_xor(ba, m);
            float os = __shfl_xor(bsg, m);
            float oi = __shfl_xor(bi, m);
            cmax(ba, bsg, bi, oa, os, oi);
        }
        if ((o & 63) == 0) hred[o >> 6] = make_float4(ba, bsg, bi, 0.f);
        __syncthreads();
        if (o == 0) {
            float4 r = hred[0], q = hred[1];
            if (q.x > r.x || (q.x == r.x && q.z < r.z)) r = q;
            const int idx = (int)r.z;
            sh_atom = idx / TOUT;
            sh_pos = idx - sh_atom * TOUT;
            sh_amp = r.y;
        }
        __syncthreads();
        pos = sh_pos; atom = sh_atom; amp = sh_amp;
    } else {
        pos  = pos_a[s * BATCH + b];
        atom = atom_a[s * BATCH + b];
        amp  = amp_a[s * BATCH + b];
    }
    const float posn = (float)pos / 32513.0f;
    float sum = br[o];
    for (int c = 0; c < 128; ++c) {
        float pa = wpa[c * 2] * posn + wpa[c * 2 + 1] * amp + bpa[c];
        float at = wat[c * 256 + atom] + bat[c];
        sum += wr[o * 256 + c] * pa + wr[o * 256 + 128 + c] * at;
    }
    out[(b * 128 + o) * NSTEP + s] = sum;
}

extern "C" void kernel_launch(void* const* d_in, const int* in_sizes, int n_in,
                              void* d_out, int out_size, void* d_ws, size_t ws_size,
                              hipStream_t stream) {
    const float* x   = (const float*)d_in[0];
    const float* d   = (const float*)d_in[1];
    const float* wpa = (const float*)d_in[2];
    const float* bpa = (const float*)d_in[3];
    const float* wat = (const float*)d_in[4];
    const float* bat = (const float*)d_in[5];
    const float* wr  = (const float*)d_in[6];
    const float* br  = (const float*)d_in[7];
    float* out = (float*)d_out;

    char* ws = (char*)d_ws;
    float4* bm = (float4*)ws;                          // 8*256*255*16 = 8,355,840 B
    float4* l2 = (float4*)(ws + 8355840);              // 2*2048*16 = 65,536 B
    int*   pos_a  = (int*)(ws + 8355840 + 65536);
    int*   atom_a = pos_a + NSTEP * BATCH;
    float* amp_a  = (float*)(atom_a + NSTEP * BATCH);

    k_init<<<dim3(8, 32, 8), 256, 0, stream>>>(x, d, bm);
    k_lvl2<<<dim3(32, 8), 256, 0, stream>>>(bm, l2);
    for (int st = 0; st < NSTEP - 1; ++st)
        k_step<<<dim3(32, 8), 512, 0, stream>>>(x, d, bm, l2, pos_a, atom_a, amp_a, st);
    k_head<<<dim3(16, 8), 128, 0, stream>>>(pos_a, atom_a, amp_a, l2,
                                            wpa, bpa, wat, bat, wr, br, out);
}